// Round 12
// baseline (413.201 us; speedup 1.0000x reference)
//
#include <hip/hip_runtime.h>

#define N_NODES 50000
#define N_EDGES 600000
#define DD 128
#define RUNE 80                      // edges per wave (5 tiles of 16)
#define NBLK_AGG 1875                // 1875*4*80 = 600000 exactly

typedef __attribute__((ext_vector_type(8))) short short8;
typedef __attribute__((ext_vector_type(4))) float f32x4;

__device__ __forceinline__ short f2bf(float f) {
    union { float f; unsigned u; } v; v.f = f;
    unsigned r = v.u + 0x7fffu + ((v.u >> 16) & 1u);
    return (short)(r >> 16);
}
__device__ __forceinline__ float u2f(unsigned u) {
    union { float f; unsigned u; } v; v.u = u;
    return v.f;
}
__device__ __forceinline__ unsigned packbf(float a, float b) {
    return ((unsigned)(unsigned short)f2bf(a)) |
           (((unsigned)(unsigned short)f2bf(b)) << 16);
}

// ---------------------------------------------------------------------------
// Streaming GEMM: Y = X @ W^T + bias -> bf16 (obj_lin). (proven)
// ---------------------------------------------------------------------------
__global__ __launch_bounds__(256) void k_lin(const float* __restrict__ X,
                                             const float* __restrict__ W,
                                             const float* __restrict__ bias,
                                             short* __restrict__ Y,
                                             int ntiles) {
    __shared__ __align__(16) short Wf[128 * 128];
    for (int i = threadIdx.x; i < 2048; i += 256) {
        const int fl = i & 63, fr = i >> 6;
        const int nt = fr >> 2, ks = fr & 3, fg = fl >> 4, fln = fl & 15;
        const float* s = W + (nt * 16 + fln) * DD + ks * 32 + fg * 8;
        short* d = Wf + i * 8;
#pragma unroll
        for (int j = 0; j < 8; ++j) d[j] = f2bf(s[j]);
    }
    __syncthreads();

    const int wave = threadIdx.x >> 6;
    const int lane = threadIdx.x & 63;
    const int g = lane >> 4, ln = lane & 15;

    float bb[8];
#pragma unroll
    for (int nt = 0; nt < 8; ++nt) bb[nt] = bias[nt * 16 + ln];

    for (int t = blockIdx.x * 4 + wave; t < ntiles; t += gridDim.x * 4) {
        const float* xr = X + (size_t)(t * 16 + ln) * DD;
        short8 a[4];
#pragma unroll
        for (int ks = 0; ks < 4; ++ks) {
            const f32x4 t0 = *(const f32x4*)(xr + ks * 32 + g * 8);
            const f32x4 t1 = *(const f32x4*)(xr + ks * 32 + g * 8 + 4);
            short8 v;
            v[0] = f2bf(t0[0]); v[1] = f2bf(t0[1]); v[2] = f2bf(t0[2]); v[3] = f2bf(t0[3]);
            v[4] = f2bf(t1[0]); v[5] = f2bf(t1[1]); v[6] = f2bf(t1[2]); v[7] = f2bf(t1[3]);
            a[ks] = v;
        }
#pragma unroll
        for (int nt = 0; nt < 8; ++nt) {
            f32x4 acc = {0.f, 0.f, 0.f, 0.f};
#pragma unroll
            for (int ks = 0; ks < 4; ++ks) {
                short8 b = *(const short8*)(Wf + (((nt << 2) + ks) * 64 + lane) * 8);
                acc = __builtin_amdgcn_mfma_f32_16x16x32_bf16(a[ks], b, acc, 0, 0, 0);
            }
#pragma unroll
            for (int r = 0; r < 4; ++r)
                Y[(size_t)(t * 16 + g * 4 + r) * DD + nt * 16 + ln] = f2bf(acc[r] + bb[nt]);
        }
    }
}

// ---------------------------------------------------------------------------
// CSR-sort construction: counts -> scan -> cursor; scatter {eid,src} + dst
// ---------------------------------------------------------------------------
__global__ __launch_bounds__(256) void k_count(const int* __restrict__ EI,
                                               int* __restrict__ counts) {
    int e = blockIdx.x * 256 + threadIdx.x;
    if (e < N_EDGES) atomicAdd(&counts[EI[2 * e + 1]], 1);
}

__global__ __launch_bounds__(256) void k_scan1(const int* __restrict__ counts,
                                               int* __restrict__ scanned,
                                               int* __restrict__ bsum) {
    __shared__ int tmp[256];
    const int t = threadIdx.x;
    const int i = blockIdx.x * 256 + t;
    int v = (i < N_NODES) ? counts[i] : 0;
    tmp[t] = v;
    __syncthreads();
#pragma unroll
    for (int off = 1; off < 256; off <<= 1) {
        int x = (t >= off) ? tmp[t - off] : 0;
        __syncthreads();
        tmp[t] += x;
        __syncthreads();
    }
    if (i < N_NODES) scanned[i] = tmp[t] - v;
    if (t == 255) bsum[blockIdx.x] = tmp[255];
}

__global__ __launch_bounds__(256) void k_scan3m(const int* __restrict__ scanned,
                                                const int* __restrict__ bsum,
                                                int* __restrict__ cursor,
                                                int nb) {
    __shared__ int red[256];
    const int t = threadIdx.x;
    const int bid = blockIdx.x;
    red[t] = (t < bid && t < nb) ? bsum[t] : 0;
    __syncthreads();
#pragma unroll
    for (int off = 128; off > 0; off >>= 1) {
        if (t < off) red[t] += red[t + off];
        __syncthreads();
    }
    const int pre = red[0];
    const int i = bid * 256 + t;
    if (i < N_NODES) cursor[i] = scanned[i] + pre;
}

__global__ __launch_bounds__(256) void k_scatter3(const int* __restrict__ EI,
                                                  int* __restrict__ cursor,
                                                  int2* __restrict__ sorted,
                                                  int* __restrict__ dsts) {
    int e = blockIdx.x * 256 + threadIdx.x;
    if (e < N_EDGES) {
        int2 sd = *(const int2*)(EI + 2 * e);
        int pos = atomicAdd(&cursor[sd.y], 1);
        sorted[pos] = make_int2(e, sd.x);       // {edge id, src}
        dsts[pos] = sd.y;
    }
}

// ---------------------------------------------------------------------------
// Fused rel-GEMM + segmented aggregation over sorted edges.
// 80-edge contiguous runs per wave; register-only segment state (no global
// loads in the state machine); prefetched A-gathers; u32 LDS staging both
// sides; plain float2 flush for run-interior segments, atomicAdd at run
// boundaries. out pre-zeroed; outer relu in k_relu (idempotent).
// ---------------------------------------------------------------------------
__global__ __launch_bounds__(256) void k_fagg2(const float* __restrict__ RV,
                                               const int2* __restrict__ sorted,
                                               const int* __restrict__ dsts,
                                               const float* __restrict__ W,
                                               const float* __restrict__ bias,
                                               const short* __restrict__ OL,
                                               float* __restrict__ out) {
    __shared__ __align__(16) short Wf[128 * 128];
    __shared__ __align__(16) unsigned stg[4][8 * 136];   // [e2][col], stride 136

    for (int i = threadIdx.x; i < 2048; i += 256) {
        const int fl = i & 63, fr = i >> 6;
        const int nt = fr >> 2, ks = fr & 3, fg = fl >> 4, fln = fl & 15;
        const float* s = W + (nt * 16 + fln) * DD + ks * 32 + fg * 8;
        short* d = Wf + i * 8;
#pragma unroll
        for (int j = 0; j < 8; ++j) d[j] = f2bf(s[j]);
    }
    __syncthreads();

    const int wave = threadIdx.x >> 6;
    const int lane = threadIdx.x & 63;
    const int g = lane >> 4, ln = lane & 15;
    unsigned* st = stg[wave];

    const int wid = blockIdx.x * 4 + wave;
    const int p0 = wid * RUNE;
    const int p1 = p0 + RUNE;                        // exact partition

    const float br0 = bias[2 * lane];
    const float br1 = bias[2 * lane + 1];
    const unsigned short* OLu = (const unsigned short*)OL;

    const bool head_shared = (p0 > 0) && (dsts[p0 - 1] == dsts[p0]);
    const bool tail_shared = (p1 < N_EDGES) && (dsts[p1] == dsts[p1 - 1]);

    int d_cur = dsts[p0];
    bool head_atomic = head_shared;
    float a0 = 0.f, a1 = 0.f;

    // prefetch tile 0
    int2 se_c = sorted[p0 + ln];
    int  dl_c = dsts[p0 + ln];
    f32x4 ar_c[8];
    {
        const float* base = RV + (size_t)se_c.x * DD;
#pragma unroll
        for (int ks = 0; ks < 4; ++ks) {
            ar_c[2 * ks]     = *(const f32x4*)(base + ks * 32 + g * 8);
            ar_c[2 * ks + 1] = *(const f32x4*)(base + ks * 32 + g * 8 + 4);
        }
    }

    for (int k = 0; k < RUNE / 16; ++k) {
        // fire next tile's loads early
        int2 se_n = se_c; int dl_n = dl_c;
        f32x4 ar_n[8];
        const bool have = (k + 1) < (RUNE / 16);
        if (have) {
            const int e0n = p0 + (k + 1) * 16;
            se_n = sorted[e0n + ln];
            dl_n = dsts[e0n + ln];
            const float* base = RV + (size_t)se_n.x * DD;
#pragma unroll
            for (int ks = 0; ks < 4; ++ks) {
                ar_n[2 * ks]     = *(const f32x4*)(base + ks * 32 + g * 8);
                ar_n[2 * ks + 1] = *(const f32x4*)(base + ks * 32 + g * 8 + 4);
            }
        }

        // convert + MFMA on current tile
        short8 af[4];
#pragma unroll
        for (int ks = 0; ks < 4; ++ks) {
            const f32x4 t0 = ar_c[2 * ks], t1 = ar_c[2 * ks + 1];
            short8 v;
            v[0] = f2bf(t0[0]); v[1] = f2bf(t0[1]); v[2] = f2bf(t0[2]); v[3] = f2bf(t0[3]);
            v[4] = f2bf(t1[0]); v[5] = f2bf(t1[1]); v[6] = f2bf(t1[2]); v[7] = f2bf(t1[3]);
            af[ks] = v;
        }
        f32x4 acc[8];
#pragma unroll
        for (int nt = 0; nt < 8; ++nt) {
            acc[nt] = (f32x4){0.f, 0.f, 0.f, 0.f};
#pragma unroll
            for (int ks = 0; ks < 4; ++ks) {
                short8 b = *(const short8*)(Wf + (((nt << 2) + ks) * 64 + lane) * 8);
                acc[nt] = __builtin_amdgcn_mfma_f32_16x16x32_bf16(af[ks], b, acc[nt], 0, 0, 0);
            }
        }

        // stage: row e2 = g*2+(r>>1); word col = nt*16+ln; lo16 = even edge
#pragma unroll
        for (int nt = 0; nt < 8; ++nt) {
            const int c = nt * 16 + ln;
            st[(g * 2) * 136 + c]     = packbf(acc[nt][0], acc[nt][1]);
            st[(g * 2 + 1) * 136 + c] = packbf(acc[nt][2], acc[nt][3]);
        }

        // epilogue: 16 edges; register-only segment state
#pragma unroll
        for (int ep = 0; ep < 8; ++ep) {
            const unsigned qx = st[ep * 136 + 2 * lane];
            const unsigned qy = st[ep * 136 + 2 * lane + 1];
#pragma unroll
            for (int sub = 0; sub < 2; ++sub) {
                const int e = 2 * ep + sub;
                const int src  = __shfl(se_c.y, e);
                const int dstv = __shfl(dl_c, e);
                if (dstv != d_cur) {                 // wave-uniform branch
                    if (head_atomic) {
                        atomicAdd(&out[(size_t)d_cur * DD + 2 * lane], a0);
                        atomicAdd(&out[(size_t)d_cur * DD + 2 * lane + 1], a1);
                        head_atomic = false;
                    } else {
                        *(float2*)(out + (size_t)d_cur * DD + 2 * lane) =
                            make_float2(a0, a1);
                    }
                    a0 = a1 = 0.f;
                    d_cur = dstv;
                }
                const float s0 = sub ? u2f(qx & 0xffff0000u) : u2f(qx << 16);
                const float s1 = sub ? u2f(qy & 0xffff0000u) : u2f(qy << 16);
                const unsigned ows = *(const unsigned*)(OLu + (size_t)src  * DD + 2 * lane);
                const unsigned owd = *(const unsigned*)(OLu + (size_t)dstv * DD + 2 * lane);
                const float m0 = s0 + br0 + u2f(ows << 16) + u2f(owd << 16);
                const float m1 = s1 + br1 + u2f(ows & 0xffff0000u) + u2f(owd & 0xffff0000u);
                a0 += fmaxf(m0, 0.f);
                a1 += fmaxf(m1, 0.f);
            }
        }

        if (have) {
            se_c = se_n; dl_c = dl_n;
#pragma unroll
            for (int q = 0; q < 8; ++q) ar_c[q] = ar_n[q];
        }
    }

    // final flush
    if (head_atomic || tail_shared) {
        atomicAdd(&out[(size_t)d_cur * DD + 2 * lane], a0);
        atomicAdd(&out[(size_t)d_cur * DD + 2 * lane + 1], a1);
    } else {
        *(float2*)(out + (size_t)d_cur * DD + 2 * lane) = make_float2(a0, a1);
    }
}

// ---------------------------------------------------------------------------
// Zero + final ReLU passes over out (relu is idempotent -> safe on both
// plain-stored and atomic-accumulated rows)
// ---------------------------------------------------------------------------
__global__ __launch_bounds__(256) void k_zerof(float4* __restrict__ p, int n4) {
    int i = blockIdx.x * 256 + threadIdx.x;
    if (i < n4) p[i] = (float4){0.f, 0.f, 0.f, 0.f};
}

__global__ __launch_bounds__(256) void k_relu(float4* __restrict__ p, int n4) {
    int i = blockIdx.x * 256 + threadIdx.x;
    if (i < n4) {
        float4 v = p[i];
        v.x = fmaxf(v.x, 0.f); v.y = fmaxf(v.y, 0.f);
        v.z = fmaxf(v.z, 0.f); v.w = fmaxf(v.w, 0.f);
        p[i] = v;
    }
}

// ---------------------------------------------------------------------------
extern "C" void kernel_launch(void* const* d_in, const int* in_sizes, int n_in,
                              void* d_out, int out_size, void* d_ws, size_t ws_size,
                              hipStream_t stream) {
    const float* obj = (const float*)d_in[0];
    const float* rel = (const float*)d_in[1];
    const int*   ei  = (const int*)d_in[2];
    const float* Wo  = (const float*)d_in[3];
    const float* bo  = (const float*)d_in[4];
    const float* Wr  = (const float*)d_in[5];
    const float* br  = (const float*)d_in[6];
    float* out = (float*)d_out;

    char* ws = (char*)d_ws;
    short* OLb     = (short*)ws;                     // 12,800,000 B
    int2*  sorted  = (int2*)(ws + 12800000);         //  4,800,000 B
    int*   dsts    = (int*)(ws + 17600000);          //  2,400,000 B
    int*   counts  = (int*)(ws + 20000000);          //    200,000 B
    int*   scanned = (int*)(ws + 20200192);          //    200,704 B
    int*   cursor  = (int*)(ws + 20400896);          //    200,000 B
    int*   bsum    = (int*)(ws + 20601088);          //      1,024 B

    const int NB_E = (N_EDGES + 255) / 256;          // 2344
    const int NB_N = (N_NODES + 255) / 256;          // 196
    const int n4 = N_NODES * DD / 4;                 // 1,600,000

    hipMemsetAsync(counts, 0, N_NODES * sizeof(int), stream);
    k_count<<<NB_E, 256, 0, stream>>>(ei, counts);
    k_scan1<<<NB_N, 256, 0, stream>>>(counts, scanned, bsum);
    k_scan3m<<<NB_N, 256, 0, stream>>>(scanned, bsum, cursor, NB_N);
    k_scatter3<<<NB_E, 256, 0, stream>>>(ei, cursor, sorted, dsts);
    k_lin<<<782, 256, 0, stream>>>(obj, Wo, bo, OLb, N_NODES / 16);
    k_zerof<<<(n4 + 255) / 256, 256, 0, stream>>>((float4*)out, n4);
    k_fagg2<<<NBLK_AGG, 256, 0, stream>>>(rel, sorted, dsts, Wr, br, OLb, out);
    k_relu<<<(n4 + 255) / 256, 256, 0, stream>>>((float4*)out, n4);
}